// Round 1
// baseline (3961.416 us; speedup 1.0000x reference)
//
#include <hip/hip_runtime.h>

#define NN 200000
#define NE 200000
#define HD 256

typedef __attribute__((ext_vector_type(8))) short short8;
typedef __attribute__((ext_vector_type(4))) short short4v;
typedef __attribute__((ext_vector_type(4))) float f32x4;

static __device__ __forceinline__ unsigned short f2bf(float f) {
  unsigned u = __float_as_uint(f);
  u = (u + 0x7FFFu + ((u >> 16) & 1u)) >> 16;
  return (unsigned short)u;
}

static __device__ __forceinline__ float sigmoidf_(float x) {
  return 1.0f / (1.0f + __expf(-x));
}
static __device__ __forceinline__ float tanhf_(float x) {
  return 2.0f / (1.0f + __expf(-2.0f * x)) - 1.0f;
}

static __device__ __forceinline__ void atomAddF(float* p, float v) {
  __hip_atomic_fetch_add(p, v, __ATOMIC_RELAXED, __HIP_MEMORY_SCOPE_AGENT);
}

// ---------------- weight prep: f32 -> bf16 (+ gate-interleaved row permute) ----
// ws layout: Wfb[256*256] bf16 | Wioub[768*256] bf16 | Uioub[768*256] bf16 | bperm[768] f32
__global__ __launch_bounds__(256) void prep_kernel(
    const float* __restrict__ Ufw, const float* __restrict__ Wiou,
    const float* __restrict__ Uiou, const float* __restrict__ biou,
    unsigned short* __restrict__ Wfb, unsigned short* __restrict__ Wioub,
    unsigned short* __restrict__ Uioub, float* __restrict__ bperm) {
  int idx = blockIdx.x * 256 + threadIdx.x;
  if (idx < 65536) {
    Wfb[idx] = f2bf(Ufw[idx]);
  } else if (idx < 262144) {
    int i2 = idx - 65536;
    int rp = i2 >> 8, k = i2 & 255;
    int T = rp >> 4, cc = rp & 15;
    int g = T % 3, tj = T / 3;  // permuted tile T = 3*tj + g
    Wioub[i2] = f2bf(Wiou[(g * 256 + tj * 16 + cc) * 256 + k]);
  } else if (idx < 458752) {
    int i2 = idx - 262144;
    int rp = i2 >> 8, k = i2 & 255;
    int T = rp >> 4, cc = rp & 15;
    int g = T % 3, tj = T / 3;
    Uioub[i2] = f2bf(Uiou[(g * 256 + tj * 16 + cc) * 256 + k]);
  } else if (idx < 459520) {
    int j2 = idx - 458752;
    int T = j2 >> 4, cc = j2 & 15;
    int g = T % 3, tj = T / 3;
    bperm[j2] = biou[g * 256 + tj * 16 + cc];
  }
}

// ---------------- edge kernel: f = sigmoid(h[src] @ Ufw^T + b), scatter-adds ---
#define F_AS 72  // LDS row stride in shorts (64 + 8 pad -> 144B, bank-balanced)
#define F_BS 72

__global__ __launch_bounds__(256) void edge_kernel(
    const float* __restrict__ h, const float* __restrict__ c,
    const unsigned short* __restrict__ Wfb, const float* __restrict__ Ufb,
    const int* __restrict__ esrc, const int* __restrict__ edst,
    float* h_tild, float* c_agg) {
  __shared__ __align__(16) unsigned short Als[64 * F_AS];
  __shared__ __align__(16) unsigned short Bls[256 * F_BS];
  __shared__ int srcl[64], dstl[64];

  const int tid = threadIdx.x;
  const int e0 = blockIdx.x * 64;
  if (tid < 64) { srcl[tid] = esrc[e0 + tid]; dstl[tid] = edst[e0 + tid]; }
  __syncthreads();

  const int lane = tid & 63;
  const int wv = tid >> 6;           // 4 waves: 2M x 2N
  const int wm = wv >> 1, wn = wv & 1;
  const int cbase = lane & 15;
  const int kg = lane >> 4;

  f32x4 acc[2][8];
#pragma unroll
  for (int i = 0; i < 2; ++i)
#pragma unroll
    for (int j = 0; j < 8; ++j) acc[i][j] = {0.f, 0.f, 0.f, 0.f};

  const int arow = tid >> 2;         // edge row 0..63
  const int acg = tid & 3;           // 16-col group
  const float* hrow = h + (size_t)srcl[arow] * HD;
  float* htrow = h_tild + (size_t)dstl[arow] * HD;

  for (int kc = 0; kc < 4; ++kc) {
    const int k0 = kc * 64;
    // stage A: gathered h rows f32 -> bf16 LDS; also scatter h_tild (f32 vals)
    const float4* s4 = (const float4*)(hrow + k0 + acg * 16);
    float4 q0 = s4[0], q1 = s4[1], q2 = s4[2], q3 = s4[3];
    short8 p0, p1;
    p0[0] = f2bf(q0.x); p0[1] = f2bf(q0.y); p0[2] = f2bf(q0.z); p0[3] = f2bf(q0.w);
    p0[4] = f2bf(q1.x); p0[5] = f2bf(q1.y); p0[6] = f2bf(q1.z); p0[7] = f2bf(q1.w);
    p1[0] = f2bf(q2.x); p1[1] = f2bf(q2.y); p1[2] = f2bf(q2.z); p1[3] = f2bf(q2.w);
    p1[4] = f2bf(q3.x); p1[5] = f2bf(q3.y); p1[6] = f2bf(q3.z); p1[7] = f2bf(q3.w);
    short8* ap = (short8*)&Als[arow * F_AS + acg * 16];
    ap[0] = p0; ap[1] = p1;
    {
      float* hp = htrow + k0 + acg * 16;
      atomAddF(hp + 0, q0.x);  atomAddF(hp + 1, q0.y);
      atomAddF(hp + 2, q0.z);  atomAddF(hp + 3, q0.w);
      atomAddF(hp + 4, q1.x);  atomAddF(hp + 5, q1.y);
      atomAddF(hp + 6, q1.z);  atomAddF(hp + 7, q1.w);
      atomAddF(hp + 8, q2.x);  atomAddF(hp + 9, q2.y);
      atomAddF(hp + 10, q2.z); atomAddF(hp + 11, q2.w);
      atomAddF(hp + 12, q3.x); atomAddF(hp + 13, q3.y);
      atomAddF(hp + 14, q3.z); atomAddF(hp + 15, q3.w);
    }
    // stage B: Ufw bf16 rows [n][k]
#pragma unroll
    for (int i = 0; i < 8; ++i) {
      int f = tid + 256 * i;
      int row = f >> 3, ch = f & 7;
      short8 vb = *(const short8*)(Wfb + row * 256 + k0 + ch * 8);
      *(short8*)&Bls[row * F_BS + ch * 8] = vb;
    }
    __syncthreads();
#pragma unroll
    for (int ks = 0; ks < 2; ++ks) {
      short8 a0 = *(const short8*)&Als[(wm * 32 + cbase) * F_AS + ks * 32 + kg * 8];
      short8 a1 = *(const short8*)&Als[(wm * 32 + 16 + cbase) * F_AS + ks * 32 + kg * 8];
#pragma unroll
      for (int nt = 0; nt < 8; ++nt) {
        short8 b = *(const short8*)&Bls[(wn * 128 + nt * 16 + cbase) * F_BS + ks * 32 + kg * 8];
        acc[0][nt] = __builtin_amdgcn_mfma_f32_16x16x32_bf16(a0, b, acc[0][nt], 0, 0, 0);
        acc[1][nt] = __builtin_amdgcn_mfma_f32_16x16x32_bf16(a1, b, acc[1][nt], 0, 0, 0);
      }
    }
    __syncthreads();
  }
  // epilogue: f = sigmoid(acc + bias); c_agg[dst] += f * c[src]
  const int rsub = kg * 4;
#pragma unroll
  for (int nt = 0; nt < 8; ++nt) {
    const int coln = wn * 128 + nt * 16 + cbase;
    const float bias = Ufb[coln];
#pragma unroll
    for (int mt = 0; mt < 2; ++mt) {
#pragma unroll
      for (int j = 0; j < 4; ++j) {
        const int el = wm * 32 + mt * 16 + rsub + j;
        const float fg = sigmoidf_(acc[mt][nt][j] + bias);
        const float cv = c[(size_t)srcl[el] * HD + coln];
        atomAddF(c_agg + (size_t)dstl[el] * HD + coln, fg * cv);
      }
    }
  }
}

// ---------------- iou kernel: iou = x@W^T + h_tild@U^T + b, fused LSTM gates ---
#define I_AS 40  // 32 + 8 pad shorts -> 80B rows
#define I_BS 40

__global__ __launch_bounds__(256) void iou_kernel(
    const float* __restrict__ x, const unsigned short* __restrict__ Wioub,
    const unsigned short* __restrict__ Uioub, const float* __restrict__ bperm,
    float* out) {
  __shared__ __align__(16) unsigned short Als[32 * I_AS];
  __shared__ __align__(16) unsigned short Bls[768 * I_BS];

  const int tid = threadIdx.x;
  const int lane = tid & 63;
  const int wv = tid >> 6;           // 4 waves: 2M x 2N (N = 384 cols each)
  const int wm = wv >> 1, wn = wv & 1;
  const int cbase = lane & 15;
  const int kg = lane >> 4;
  const int r0 = blockIdx.x * 32;

  float* h_tild = out;                       // h-half holds h_tild (pre-accumulated)
  float* c_agg = out + (size_t)NN * HD;      // c-half holds c_agg

  f32x4 acc[24];
#pragma unroll
  for (int t = 0; t < 24; ++t) acc[t] = {0.f, 0.f, 0.f, 0.f};

  const int arow = tid >> 3;  // 0..31
  const int acg = tid & 7;    // 4-col group

  for (int pass = 0; pass < 2; ++pass) {
    const float* As = pass ? h_tild : x;
    const unsigned short* Bs = pass ? Uioub : Wioub;
    for (int kc = 0; kc < 8; ++kc) {
      const int k0 = kc * 32;
      float4 q = *(const float4*)(As + (size_t)(r0 + arow) * HD + k0 + acg * 4);
      short4v p;
      p[0] = f2bf(q.x); p[1] = f2bf(q.y); p[2] = f2bf(q.z); p[3] = f2bf(q.w);
      *(short4v*)&Als[arow * I_AS + acg * 4] = p;
#pragma unroll
      for (int i = 0; i < 12; ++i) {
        int f = tid + 256 * i;
        int row = f >> 2, ch = f & 3;
        short8 vb = *(const short8*)(Bs + row * 256 + k0 + ch * 8);
        *(short8*)&Bls[row * I_BS + ch * 8] = vb;
      }
      __syncthreads();
      short8 a = *(const short8*)&Als[(wm * 16 + cbase) * I_AS + kg * 8];
#pragma unroll
      for (int tt = 0; tt < 24; ++tt) {
        short8 b = *(const short8*)&Bls[((wn * 24 + tt) * 16 + cbase) * I_BS + kg * 8];
        acc[tt] = __builtin_amdgcn_mfma_f32_16x16x32_bf16(a, b, acc[tt], 0, 0, 0);
      }
      __syncthreads();
    }
  }
  // epilogue: lane holds (i,o,u) triples in consecutive acc tiles
  const int rsub = kg * 4;
#pragma unroll
  for (int t3 = 0; t3 < 8; ++t3) {
    const int T = wn * 24 + 3 * t3;
    const float bi = bperm[(T + 0) * 16 + cbase];
    const float bo = bperm[(T + 1) * 16 + cbase];
    const float bu = bperm[(T + 2) * 16 + cbase];
    const int j = (wn * 8 + t3) * 16 + cbase;  // original column 0..255
#pragma unroll
    for (int jr = 0; jr < 4; ++jr) {
      const int r = r0 + wm * 16 + rsub + jr;
      const size_t idx = (size_t)r * HD + j;
      const float iv = sigmoidf_(acc[3 * t3 + 0][jr] + bi);
      const float ov = sigmoidf_(acc[3 * t3 + 1][jr] + bo);
      const float uv = tanhf_(acc[3 * t3 + 2][jr] + bu);
      const float cn = iv * uv + c_agg[idx];
      out[idx] = ov * tanhf_(cn);   // h_new (h_tild reads for this row are done)
      c_agg[idx] = cn;              // c_new
    }
  }
}

extern "C" void kernel_launch(void* const* d_in, const int* in_sizes, int n_in,
                              void* d_out, int out_size, void* d_ws, size_t ws_size,
                              hipStream_t stream) {
  const float* x    = (const float*)d_in[0];
  const float* h    = (const float*)d_in[1];
  const float* c    = (const float*)d_in[2];
  const float* Wiou = (const float*)d_in[3];
  const float* Uiou = (const float*)d_in[4];
  const float* biou = (const float*)d_in[5];
  const float* Ufw  = (const float*)d_in[6];
  const float* Ufb  = (const float*)d_in[7];
  const int* esrc   = (const int*)d_in[8];
  const int* edst   = (const int*)d_in[9];
  float* out = (float*)d_out;

  unsigned short* Wfb   = (unsigned short*)d_ws;
  unsigned short* Wioub = (unsigned short*)((char*)d_ws + 131072);
  unsigned short* Uioub = (unsigned short*)((char*)d_ws + 524288);
  float* bperm          = (float*)((char*)d_ws + 917504);

  // d_out doubles as accumulators: [0,NN*HD) = h_tild, [NN*HD, 2*NN*HD) = c_agg
  hipMemsetAsync(d_out, 0, (size_t)out_size * sizeof(float), stream);
  prep_kernel<<<1795, 256, 0, stream>>>(Ufw, Wiou, Uiou, biou, Wfb, Wioub, Uioub, bperm);
  edge_kernel<<<NE / 64, 256, 0, stream>>>(h, c, Wfb, Ufb, esrc, edst,
                                           out, out + (size_t)NN * HD);
  iou_kernel<<<NN / 32, 256, 0, stream>>>(x, Wioub, Uioub, bperm, out);
}

// Round 2
// 795.768 us; speedup vs baseline: 4.9781x; 4.9781x over previous
//
#include <hip/hip_runtime.h>

#define NN 200000
#define NE 200000
#define HD 256

typedef __attribute__((ext_vector_type(8))) short short8;
typedef __attribute__((ext_vector_type(4))) short short4v;
typedef __attribute__((ext_vector_type(4))) float f32x4;

static __device__ __forceinline__ unsigned short f2bf(float f) {
  unsigned u = __float_as_uint(f);
  u = (u + 0x7FFFu + ((u >> 16) & 1u)) >> 16;
  return (unsigned short)u;
}
static __device__ __forceinline__ float bf2f(unsigned short u) {
  return __uint_as_float(((unsigned)u) << 16);
}
static __device__ __forceinline__ float sigmoidf_(float x) {
  return 1.0f / (1.0f + __expf(-x));
}
static __device__ __forceinline__ float tanhf_(float x) {
  return 2.0f / (1.0f + __expf(-2.0f * x)) - 1.0f;
}
static __device__ __forceinline__ void atomAddF(float* p, float v) {
  __hip_atomic_fetch_add(p, v, __ATOMIC_RELAXED, __HIP_MEMORY_SCOPE_AGENT);
}
static __device__ __forceinline__ int atomAddI(int* p, int v) {
  return __hip_atomic_fetch_add(p, v, __ATOMIC_RELAXED, __HIP_MEMORY_SCOPE_AGENT);
}

// ws layout (bytes)
#define OFF_WFB    0u
#define OFF_WIOU   131072u
#define OFF_UIOU   524288u
#define OFF_BPERM  917504u
#define OFF_ROWPTR 920576u      // int[NN+1]
#define OFF_NEXT   1720832u     // int[NN] (doubles as histogram counts)
#define OFF_SLOT   2520832u     // int[NE]
#define OFF_PSRC   3320832u     // int[NE]
#define OFF_BSUM   4120832u     // int[256]
#define OFF_FC     4121856u     // bf16[NE*HD]
#define WS_NEED    106521856ull

// ---------------- weight prep: f32 -> bf16 (+ gate-interleaved row permute) ----
__global__ __launch_bounds__(256) void prep_kernel(
    const float* __restrict__ Ufw, const float* __restrict__ Wiou,
    const float* __restrict__ Uiou, const float* __restrict__ biou,
    unsigned short* __restrict__ Wfb, unsigned short* __restrict__ Wioub,
    unsigned short* __restrict__ Uioub, float* __restrict__ bperm) {
  int idx = blockIdx.x * 256 + threadIdx.x;
  if (idx < 65536) {
    Wfb[idx] = f2bf(Ufw[idx]);
  } else if (idx < 262144) {
    int i2 = idx - 65536;
    int rp = i2 >> 8, k = i2 & 255;
    int T = rp >> 4, cc = rp & 15;
    int g = T % 3, tj = T / 3;  // permuted tile T = 3*tj + g
    Wioub[i2] = f2bf(Wiou[(g * 256 + tj * 16 + cc) * 256 + k]);
  } else if (idx < 458752) {
    int i2 = idx - 262144;
    int rp = i2 >> 8, k = i2 & 255;
    int T = rp >> 4, cc = rp & 15;
    int g = T % 3, tj = T / 3;
    Uioub[i2] = f2bf(Uiou[(g * 256 + tj * 16 + cc) * 256 + k]);
  } else if (idx < 459520) {
    int j2 = idx - 458752;
    int T = j2 >> 4, cc = j2 & 15;
    int g = T % 3, tj = T / 3;
    bperm[j2] = biou[g * 256 + tj * 16 + cc];
  }
}

// ---------------- CSR build ----------------
__global__ __launch_bounds__(256) void hist_kernel(const int* __restrict__ edst,
                                                   int* __restrict__ cnt) {
  int e = blockIdx.x * 256 + threadIdx.x;
  if (e < NE) atomAddI(&cnt[edst[e]], 1);
}

__global__ __launch_bounds__(256) void scan_part(const int* __restrict__ cnt,
                                                 int* __restrict__ rp,
                                                 int* __restrict__ bsum) {
  __shared__ int sd[256];
  int t = threadIdx.x;
  int base = blockIdx.x * 1024 + t * 4;
  int v0 = (base + 0 < NN) ? cnt[base + 0] : 0;
  int v1 = (base + 1 < NN) ? cnt[base + 1] : 0;
  int v2 = (base + 2 < NN) ? cnt[base + 2] : 0;
  int v3 = (base + 3 < NN) ? cnt[base + 3] : 0;
  int s = v0 + v1 + v2 + v3;
  sd[t] = s;
  __syncthreads();
  for (int off = 1; off < 256; off <<= 1) {
    int add = (t >= off) ? sd[t - off] : 0;
    __syncthreads();
    sd[t] += add;
    __syncthreads();
  }
  int run = sd[t] - s;  // exclusive
  if (base + 0 < NN) rp[base + 0] = run; run += v0;
  if (base + 1 < NN) rp[base + 1] = run; run += v1;
  if (base + 2 < NN) rp[base + 2] = run; run += v2;
  if (base + 3 < NN) rp[base + 3] = run;
  if (t == 255) bsum[blockIdx.x] = sd[255];
}

__global__ __launch_bounds__(256) void scan_top(int* __restrict__ bsum,
                                                int* __restrict__ rp, int nb) {
  __shared__ int sd[256];
  int t = threadIdx.x;
  int v = (t < nb) ? bsum[t] : 0;
  sd[t] = v;
  __syncthreads();
  for (int off = 1; off < 256; off <<= 1) {
    int add = (t >= off) ? sd[t - off] : 0;
    __syncthreads();
    sd[t] += add;
    __syncthreads();
  }
  bsum[t] = sd[t] - v;  // exclusive block offsets
  if (t == 0) rp[NN] = NE;
}

__global__ __launch_bounds__(256) void scan_add(int* __restrict__ rp,
                                                const int* __restrict__ bsum,
                                                int* __restrict__ nxt) {
  int t = threadIdx.x;
  int base = blockIdx.x * 1024 + t * 4;
  int off = bsum[blockIdx.x];
#pragma unroll
  for (int j = 0; j < 4; ++j) {
    int i = base + j;
    if (i < NN) {
      int val = rp[i] + off;
      rp[i] = val;
      nxt[i] = val;
    }
  }
}

__global__ __launch_bounds__(256) void scatter_kernel(
    const int* __restrict__ esrc, const int* __restrict__ edst,
    int* __restrict__ nxt, int* __restrict__ slotArr, int* __restrict__ psrc) {
  int e = blockIdx.x * 256 + threadIdx.x;
  if (e < NE) {
    int d = edst[e];
    int pos = atomAddI(&nxt[d], 1);
    slotArr[e] = pos;
    psrc[pos] = esrc[e];
  }
}

// ---------------- edge kernel (fast path): fc[slot] = sigmoid(h[src]@Ufw^T+b)*c[src]
#define F_AS 72
#define F_BS 72

__global__ __launch_bounds__(256) void edge_fc_kernel(
    const float* __restrict__ h, const float* __restrict__ c,
    const unsigned short* __restrict__ Wfb, const float* __restrict__ Ufb,
    const int* __restrict__ esrc, const int* __restrict__ slotArr,
    unsigned short* __restrict__ fcb) {
  __shared__ __align__(16) unsigned short Als[64 * F_AS];
  __shared__ __align__(16) unsigned short Bls[256 * F_BS];
  __shared__ int srcl[64], slotl[64];

  const int tid = threadIdx.x;
  const int e0 = blockIdx.x * 64;
  if (tid < 64) { srcl[tid] = esrc[e0 + tid]; slotl[tid] = slotArr[e0 + tid]; }
  __syncthreads();

  const int lane = tid & 63;
  const int wv = tid >> 6;
  const int wm = wv >> 1, wn = wv & 1;
  const int cbase = lane & 15;
  const int kg = lane >> 4;

  f32x4 acc[2][8];
#pragma unroll
  for (int i = 0; i < 2; ++i)
#pragma unroll
    for (int j = 0; j < 8; ++j) acc[i][j] = {0.f, 0.f, 0.f, 0.f};

  const int arow = tid >> 2;
  const int acg = tid & 3;
  const float* hrow = h + (size_t)srcl[arow] * HD;

  for (int kc = 0; kc < 4; ++kc) {
    const int k0 = kc * 64;
    const float4* s4 = (const float4*)(hrow + k0 + acg * 16);
    float4 q0 = s4[0], q1 = s4[1], q2 = s4[2], q3 = s4[3];
    short8 p0, p1;
    p0[0] = f2bf(q0.x); p0[1] = f2bf(q0.y); p0[2] = f2bf(q0.z); p0[3] = f2bf(q0.w);
    p0[4] = f2bf(q1.x); p0[5] = f2bf(q1.y); p0[6] = f2bf(q1.z); p0[7] = f2bf(q1.w);
    p1[0] = f2bf(q2.x); p1[1] = f2bf(q2.y); p1[2] = f2bf(q2.z); p1[3] = f2bf(q2.w);
    p1[4] = f2bf(q3.x); p1[5] = f2bf(q3.y); p1[6] = f2bf(q3.z); p1[7] = f2bf(q3.w);
    short8* ap = (short8*)&Als[arow * F_AS + acg * 16];
    ap[0] = p0; ap[1] = p1;
#pragma unroll
    for (int i = 0; i < 8; ++i) {
      int f = tid + 256 * i;
      int row = f >> 3, ch = f & 7;
      short8 vb = *(const short8*)(Wfb + row * 256 + k0 + ch * 8);
      *(short8*)&Bls[row * F_BS + ch * 8] = vb;
    }
    __syncthreads();
#pragma unroll
    for (int ks = 0; ks < 2; ++ks) {
      short8 a0 = *(const short8*)&Als[(wm * 32 + cbase) * F_AS + ks * 32 + kg * 8];
      short8 a1 = *(const short8*)&Als[(wm * 32 + 16 + cbase) * F_AS + ks * 32 + kg * 8];
#pragma unroll
      for (int nt = 0; nt < 8; ++nt) {
        short8 b = *(const short8*)&Bls[(wn * 128 + nt * 16 + cbase) * F_BS + ks * 32 + kg * 8];
        acc[0][nt] = __builtin_amdgcn_mfma_f32_16x16x32_bf16(a0, b, acc[0][nt], 0, 0, 0);
        acc[1][nt] = __builtin_amdgcn_mfma_f32_16x16x32_bf16(a1, b, acc[1][nt], 0, 0, 0);
      }
    }
    __syncthreads();
  }
  const int rsub = kg * 4;
#pragma unroll
  for (int nt = 0; nt < 8; ++nt) {
    const int coln = wn * 128 + nt * 16 + cbase;
    const float bias = Ufb[coln];
#pragma unroll
    for (int mt = 0; mt < 2; ++mt) {
#pragma unroll
      for (int j = 0; j < 4; ++j) {
        const int el = wm * 32 + mt * 16 + rsub + j;
        const float fg = sigmoidf_(acc[mt][nt][j] + bias);
        const float cv = c[(size_t)srcl[el] * HD + coln];
        fcb[(size_t)slotl[el] * HD + coln] = f2bf(fg * cv);
      }
    }
  }
}

// ---------------- fused gather + iou kernel (fast path) ----------------
// 64 nodes/block, 512 threads (8 waves: 2M x 4N).
// LDS: Bls 768x40 (61440B) + Hls 64x256 swizzled (32768B) + Cls 64x258 (33024B)
#define HLS_SWZ(row, byteoff) (((row) * 512 + (byteoff)) ^ (((row) & 7) << 4))

__global__ __launch_bounds__(512) void iou_fused_kernel(
    const float* __restrict__ x, const float* __restrict__ h,
    const unsigned short* __restrict__ Wioub, const unsigned short* __restrict__ Uioub,
    const float* __restrict__ bperm, const int* __restrict__ rp,
    const int* __restrict__ psrc, const unsigned short* __restrict__ fcb,
    float* __restrict__ out) {
  __shared__ __align__(16) unsigned short Bls[768 * 40];
  __shared__ __align__(16) unsigned char HlsB[64 * 512];
  __shared__ __align__(4) unsigned short Cls[64 * 258];

  const int tid = threadIdx.x;
  const int r0 = blockIdx.x * 64;

  // ---- preamble: gather children; h_tild -> Hls (bf16), c_agg -> Cls (bf16) ----
  {
    const int node = tid >> 3;  // 0..63
    const int cg = tid & 7;     // 32 cols each
    const int n = r0 + node;
    const int s0 = rp[n], s1 = rp[n + 1];
    float4 hs[8], cs[8];
#pragma unroll
    for (int q = 0; q < 8; ++q) { hs[q] = {0.f, 0.f, 0.f, 0.f}; cs[q] = {0.f, 0.f, 0.f, 0.f}; }
    for (int s = s0; s < s1; ++s) {
      const int src = psrc[s];
      const float4* hp = (const float4*)(h + (size_t)src * HD + cg * 32);
#pragma unroll
      for (int q = 0; q < 8; ++q) {
        float4 v = hp[q];
        hs[q].x += v.x; hs[q].y += v.y; hs[q].z += v.z; hs[q].w += v.w;
      }
      const short8* fp = (const short8*)(fcb + (size_t)s * HD + cg * 32);
#pragma unroll
      for (int q = 0; q < 4; ++q) {
        short8 w = fp[q];
        cs[2 * q].x     += bf2f((unsigned short)w[0]);
        cs[2 * q].y     += bf2f((unsigned short)w[1]);
        cs[2 * q].z     += bf2f((unsigned short)w[2]);
        cs[2 * q].w     += bf2f((unsigned short)w[3]);
        cs[2 * q + 1].x += bf2f((unsigned short)w[4]);
        cs[2 * q + 1].y += bf2f((unsigned short)w[5]);
        cs[2 * q + 1].z += bf2f((unsigned short)w[6]);
        cs[2 * q + 1].w += bf2f((unsigned short)w[7]);
      }
    }
#pragma unroll
    for (int q = 0; q < 4; ++q) {
      short8 hp8;
      hp8[0] = f2bf(hs[2 * q].x);     hp8[1] = f2bf(hs[2 * q].y);
      hp8[2] = f2bf(hs[2 * q].z);     hp8[3] = f2bf(hs[2 * q].w);
      hp8[4] = f2bf(hs[2 * q + 1].x); hp8[5] = f2bf(hs[2 * q + 1].y);
      hp8[6] = f2bf(hs[2 * q + 1].z); hp8[7] = f2bf(hs[2 * q + 1].w);
      *(short8*)&HlsB[HLS_SWZ(node, cg * 64 + q * 16)] = hp8;
      unsigned short* cd = &Cls[node * 258 + cg * 32 + q * 8];
      cd[0] = f2bf(cs[2 * q].x);     cd[1] = f2bf(cs[2 * q].y);
      cd[2] = f2bf(cs[2 * q].z);     cd[3] = f2bf(cs[2 * q].w);
      cd[4] = f2bf(cs[2 * q + 1].x); cd[5] = f2bf(cs[2 * q + 1].y);
      cd[6] = f2bf(cs[2 * q + 1].z); cd[7] = f2bf(cs[2 * q + 1].w);
    }
  }
  __syncthreads();

  const int lane = tid & 63;
  const int wv = tid >> 6;    // 8 waves
  const int wm = wv >> 2;     // 2 M-groups of 32 rows
  const int wn = wv & 3;      // 4 N-groups of 12 tiles (192 cols)
  const int cbase = lane & 15;
  const int kg = lane >> 4;

  f32x4 acc[2][12];
#pragma unroll
  for (int m = 0; m < 2; ++m)
#pragma unroll
    for (int t = 0; t < 12; ++t) acc[m][t] = {0.f, 0.f, 0.f, 0.f};

  for (int pass = 0; pass < 2; ++pass) {
    const unsigned short* Bs = pass ? Uioub : Wioub;
    for (int kc = 0; kc < 8; ++kc) {
      const int k0 = kc * 32;
#pragma unroll
      for (int i = 0; i < 6; ++i) {
        int f = tid + 512 * i;
        int row = f >> 2, ch = f & 3;
        short8 vb = *(const short8*)(Bs + row * 256 + k0 + ch * 8);
        *(short8*)&Bls[row * 40 + ch * 8] = vb;
      }
      short8 a0, a1;
      if (pass == 0) {
        // read x A-fragments straight from global (L1-cached across wn dup)
        const float4* xp0 = (const float4*)(x + (size_t)(r0 + wm * 32 + cbase) * HD + k0 + kg * 8);
        const float4* xp1 = (const float4*)(x + (size_t)(r0 + wm * 32 + 16 + cbase) * HD + k0 + kg * 8);
        float4 u0 = xp0[0], u1 = xp0[1], u2 = xp1[0], u3 = xp1[1];
        a0[0] = f2bf(u0.x); a0[1] = f2bf(u0.y); a0[2] = f2bf(u0.z); a0[3] = f2bf(u0.w);
        a0[4] = f2bf(u1.x); a0[5] = f2bf(u1.y); a0[6] = f2bf(u1.z); a0[7] = f2bf(u1.w);
        a1[0] = f2bf(u2.x); a1[1] = f2bf(u2.y); a1[2] = f2bf(u2.z); a1[3] = f2bf(u2.w);
        a1[4] = f2bf(u3.x); a1[5] = f2bf(u3.y); a1[6] = f2bf(u3.z); a1[7] = f2bf(u3.w);
      }
      __syncthreads();
      if (pass == 1) {
        a0 = *(const short8*)&HlsB[HLS_SWZ(wm * 32 + cbase, k0 * 2 + kg * 16)];
        a1 = *(const short8*)&HlsB[HLS_SWZ(wm * 32 + 16 + cbase, k0 * 2 + kg * 16)];
      }
#pragma unroll
      for (int tt = 0; tt < 12; ++tt) {
        short8 b = *(const short8*)&Bls[((wn * 12 + tt) * 16 + cbase) * 40 + kg * 8];
        acc[0][tt] = __builtin_amdgcn_mfma_f32_16x16x32_bf16(a0, b, acc[0][tt], 0, 0, 0);
        acc[1][tt] = __builtin_amdgcn_mfma_f32_16x16x32_bf16(a1, b, acc[1][tt], 0, 0, 0);
      }
      __syncthreads();
    }
  }

  // ---- epilogue: gates + outputs ----
  const int rsub = kg * 4;
#pragma unroll
  for (int t3 = 0; t3 < 4; ++t3) {
    const int T = wn * 12 + 3 * t3;
    const float bi = bperm[(T + 0) * 16 + cbase];
    const float bo = bperm[(T + 1) * 16 + cbase];
    const float bu = bperm[(T + 2) * 16 + cbase];
    const int j = (wn * 4 + t3) * 16 + cbase;
#pragma unroll
    for (int mf = 0; mf < 2; ++mf) {
#pragma unroll
      for (int jr = 0; jr < 4; ++jr) {
        const int rl = wm * 32 + mf * 16 + rsub + jr;
        const size_t idx = (size_t)(r0 + rl) * HD + j;
        const float iv = sigmoidf_(acc[mf][3 * t3 + 0][jr] + bi);
        const float ov = sigmoidf_(acc[mf][3 * t3 + 1][jr] + bo);
        const float uv = tanhf_(acc[mf][3 * t3 + 2][jr] + bu);
        const float cagg = bf2f(Cls[rl * 258 + j]);
        const float cn = iv * uv + cagg;
        out[idx] = ov * tanhf_(cn);
        out[(size_t)NN * HD + idx] = cn;
      }
    }
  }
}

// ================= fallback path (R1 kernels, used when ws is too small) ======
__global__ __launch_bounds__(256) void edge_kernel(
    const float* __restrict__ h, const float* __restrict__ c,
    const unsigned short* __restrict__ Wfb, const float* __restrict__ Ufb,
    const int* __restrict__ esrc, const int* __restrict__ edst,
    float* h_tild, float* c_agg) {
  __shared__ __align__(16) unsigned short Als[64 * F_AS];
  __shared__ __align__(16) unsigned short Bls[256 * F_BS];
  __shared__ int srcl[64], dstl[64];

  const int tid = threadIdx.x;
  const int e0 = blockIdx.x * 64;
  if (tid < 64) { srcl[tid] = esrc[e0 + tid]; dstl[tid] = edst[e0 + tid]; }
  __syncthreads();

  const int lane = tid & 63;
  const int wv = tid >> 6;
  const int wm = wv >> 1, wn = wv & 1;
  const int cbase = lane & 15;
  const int kg = lane >> 4;

  f32x4 acc[2][8];
#pragma unroll
  for (int i = 0; i < 2; ++i)
#pragma unroll
    for (int j = 0; j < 8; ++j) acc[i][j] = {0.f, 0.f, 0.f, 0.f};

  const int arow = tid >> 2;
  const int acg = tid & 3;
  const float* hrow = h + (size_t)srcl[arow] * HD;
  float* htrow = h_tild + (size_t)dstl[arow] * HD;

  for (int kc = 0; kc < 4; ++kc) {
    const int k0 = kc * 64;
    const float4* s4 = (const float4*)(hrow + k0 + acg * 16);
    float4 q0 = s4[0], q1 = s4[1], q2 = s4[2], q3 = s4[3];
    short8 p0, p1;
    p0[0] = f2bf(q0.x); p0[1] = f2bf(q0.y); p0[2] = f2bf(q0.z); p0[3] = f2bf(q0.w);
    p0[4] = f2bf(q1.x); p0[5] = f2bf(q1.y); p0[6] = f2bf(q1.z); p0[7] = f2bf(q1.w);
    p1[0] = f2bf(q2.x); p1[1] = f2bf(q2.y); p1[2] = f2bf(q2.z); p1[3] = f2bf(q2.w);
    p1[4] = f2bf(q3.x); p1[5] = f2bf(q3.y); p1[6] = f2bf(q3.z); p1[7] = f2bf(q3.w);
    short8* ap = (short8*)&Als[arow * F_AS + acg * 16];
    ap[0] = p0; ap[1] = p1;
    {
      float* hp = htrow + k0 + acg * 16;
      atomAddF(hp + 0, q0.x);  atomAddF(hp + 1, q0.y);
      atomAddF(hp + 2, q0.z);  atomAddF(hp + 3, q0.w);
      atomAddF(hp + 4, q1.x);  atomAddF(hp + 5, q1.y);
      atomAddF(hp + 6, q1.z);  atomAddF(hp + 7, q1.w);
      atomAddF(hp + 8, q2.x);  atomAddF(hp + 9, q2.y);
      atomAddF(hp + 10, q2.z); atomAddF(hp + 11, q2.w);
      atomAddF(hp + 12, q3.x); atomAddF(hp + 13, q3.y);
      atomAddF(hp + 14, q3.z); atomAddF(hp + 15, q3.w);
    }
#pragma unroll
    for (int i = 0; i < 8; ++i) {
      int f = tid + 256 * i;
      int row = f >> 3, ch = f & 7;
      short8 vb = *(const short8*)(Wfb + row * 256 + k0 + ch * 8);
      *(short8*)&Bls[row * F_BS + ch * 8] = vb;
    }
    __syncthreads();
#pragma unroll
    for (int ks = 0; ks < 2; ++ks) {
      short8 a0 = *(const short8*)&Als[(wm * 32 + cbase) * F_AS + ks * 32 + kg * 8];
      short8 a1 = *(const short8*)&Als[(wm * 32 + 16 + cbase) * F_AS + ks * 32 + kg * 8];
#pragma unroll
      for (int nt = 0; nt < 8; ++nt) {
        short8 b = *(const short8*)&Bls[(wn * 128 + nt * 16 + cbase) * F_BS + ks * 32 + kg * 8];
        acc[0][nt] = __builtin_amdgcn_mfma_f32_16x16x32_bf16(a0, b, acc[0][nt], 0, 0, 0);
        acc[1][nt] = __builtin_amdgcn_mfma_f32_16x16x32_bf16(a1, b, acc[1][nt], 0, 0, 0);
      }
    }
    __syncthreads();
  }
  const int rsub = kg * 4;
#pragma unroll
  for (int nt = 0; nt < 8; ++nt) {
    const int coln = wn * 128 + nt * 16 + cbase;
    const float bias = Ufb[coln];
#pragma unroll
    for (int mt = 0; mt < 2; ++mt) {
#pragma unroll
      for (int j = 0; j < 4; ++j) {
        const int el = wm * 32 + mt * 16 + rsub + j;
        const float fg = sigmoidf_(acc[mt][nt][j] + bias);
        const float cv = c[(size_t)srcl[el] * HD + coln];
        atomAddF(c_agg + (size_t)dstl[el] * HD + coln, fg * cv);
      }
    }
  }
}

#define I_AS 40
#define I_BS 40

__global__ __launch_bounds__(256) void iou_kernel(
    const float* __restrict__ x, const unsigned short* __restrict__ Wioub,
    const unsigned short* __restrict__ Uioub, const float* __restrict__ bperm,
    float* out) {
  __shared__ __align__(16) unsigned short Als[32 * I_AS];
  __shared__ __align__(16) unsigned short Bls[768 * I_BS];

  const int tid = threadIdx.x;
  const int lane = tid & 63;
  const int wv = tid >> 6;
  const int wm = wv >> 1, wn = wv & 1;
  const int cbase = lane & 15;
  const int kg = lane >> 4;
  const int r0 = blockIdx.x * 32;

  float* h_tild = out;
  float* c_agg = out + (size_t)NN * HD;

  f32x4 acc[24];
#pragma unroll
  for (int t = 0; t < 24; ++t) acc[t] = {0.f, 0.f, 0.f, 0.f};

  const int arow = tid >> 3;
  const int acg = tid & 7;

  for (int pass = 0; pass < 2; ++pass) {
    const float* As = pass ? h_tild : x;
    const unsigned short* Bs = pass ? Uioub : Wioub;
    for (int kc = 0; kc < 8; ++kc) {
      const int k0 = kc * 32;
      float4 q = *(const float4*)(As + (size_t)(r0 + arow) * HD + k0 + acg * 4);
      short4v p;
      p[0] = f2bf(q.x); p[1] = f2bf(q.y); p[2] = f2bf(q.z); p[3] = f2bf(q.w);
      *(short4v*)&Als[arow * I_AS + acg * 4] = p;
#pragma unroll
      for (int i = 0; i < 12; ++i) {
        int f = tid + 256 * i;
        int row = f >> 2, ch = f & 3;
        short8 vb = *(const short8*)(Bs + row * 256 + k0 + ch * 8);
        *(short8*)&Bls[row * I_BS + ch * 8] = vb;
      }
      __syncthreads();
      short8 a = *(const short8*)&Als[(wm * 16 + cbase) * I_AS + kg * 8];
#pragma unroll
      for (int tt = 0; tt < 24; ++tt) {
        short8 b = *(const short8*)&Bls[((wn * 24 + tt) * 16 + cbase) * I_BS + kg * 8];
        acc[tt] = __builtin_amdgcn_mfma_f32_16x16x32_bf16(a, b, acc[tt], 0, 0, 0);
      }
      __syncthreads();
    }
  }
  const int rsub = kg * 4;
#pragma unroll
  for (int t3 = 0; t3 < 8; ++t3) {
    const int T = wn * 24 + 3 * t3;
    const float bi = bperm[(T + 0) * 16 + cbase];
    const float bo = bperm[(T + 1) * 16 + cbase];
    const float bu = bperm[(T + 2) * 16 + cbase];
    const int j = (wn * 8 + t3) * 16 + cbase;
#pragma unroll
    for (int jr = 0; jr < 4; ++jr) {
      const int r = r0 + wm * 16 + rsub + jr;
      const size_t idx = (size_t)r * HD + j;
      const float iv = sigmoidf_(acc[3 * t3 + 0][jr] + bi);
      const float ov = sigmoidf_(acc[3 * t3 + 1][jr] + bo);
      const float uv = tanhf_(acc[3 * t3 + 2][jr] + bu);
      const float cn = iv * uv + c_agg[idx];
      out[idx] = ov * tanhf_(cn);
      c_agg[idx] = cn;
    }
  }
}

extern "C" void kernel_launch(void* const* d_in, const int* in_sizes, int n_in,
                              void* d_out, int out_size, void* d_ws, size_t ws_size,
                              hipStream_t stream) {
  const float* x    = (const float*)d_in[0];
  const float* h    = (const float*)d_in[1];
  const float* c    = (const float*)d_in[2];
  const float* Wiou = (const float*)d_in[3];
  const float* Uiou = (const float*)d_in[4];
  const float* biou = (const float*)d_in[5];
  const float* Ufw  = (const float*)d_in[6];
  const float* Ufb  = (const float*)d_in[7];
  const int* esrc   = (const int*)d_in[8];
  const int* edst   = (const int*)d_in[9];
  float* out = (float*)d_out;

  char* ws = (char*)d_ws;
  unsigned short* Wfb   = (unsigned short*)(ws + OFF_WFB);
  unsigned short* Wioub = (unsigned short*)(ws + OFF_WIOU);
  unsigned short* Uioub = (unsigned short*)(ws + OFF_UIOU);
  float* bperm          = (float*)(ws + OFF_BPERM);

  if (ws_size >= WS_NEED) {
    int* rpp  = (int*)(ws + OFF_ROWPTR);
    int* nxt  = (int*)(ws + OFF_NEXT);
    int* slot = (int*)(ws + OFF_SLOT);
    int* psrc = (int*)(ws + OFF_PSRC);
    int* bsum = (int*)(ws + OFF_BSUM);
    unsigned short* fcb = (unsigned short*)(ws + OFF_FC);

    hipMemsetAsync(nxt, 0, (size_t)NN * sizeof(int), stream);
    prep_kernel<<<1795, 256, 0, stream>>>(Ufw, Wiou, Uiou, biou, Wfb, Wioub, Uioub, bperm);
    hist_kernel<<<(NE + 255) / 256, 256, 0, stream>>>(edst, nxt);
    scan_part<<<(NN + 1023) / 1024, 256, 0, stream>>>(nxt, rpp, bsum);
    scan_top<<<1, 256, 0, stream>>>(bsum, rpp, (NN + 1023) / 1024);
    scan_add<<<(NN + 1023) / 1024, 256, 0, stream>>>(rpp, bsum, nxt);
    scatter_kernel<<<(NE + 255) / 256, 256, 0, stream>>>(esrc, edst, nxt, slot, psrc);
    edge_fc_kernel<<<NE / 64, 256, 0, stream>>>(h, c, Wfb, Ufb, esrc, slot, fcb);
    iou_fused_kernel<<<NN / 64, 512, 0, stream>>>(x, h, Wioub, Uioub, bperm, rpp, psrc, fcb, out);
  } else {
    // fallback: R1 scatter-atomic path
    hipMemsetAsync(d_out, 0, (size_t)out_size * sizeof(float), stream);
    prep_kernel<<<1795, 256, 0, stream>>>(Ufw, Wiou, Uiou, biou, Wfb, Wioub, Uioub, bperm);
    edge_kernel<<<NE / 64, 256, 0, stream>>>(h, c, Wfb, Ufb, esrc, edst,
                                             out, out + (size_t)NN * HD);
    iou_kernel<<<NN / 32, 256, 0, stream>>>(x, Wioub, Uioub, bperm, out);
  }
}